// Round 5
// baseline (134.033 us; speedup 1.0000x reference)
//
#include <hip/hip_runtime.h>

namespace {

constexpr int Dh   = 64;
constexpr int Sseq = 2048;
constexpr int NT   = Sseq / 64;     // 32 q-tiles per head
constexpr int BH   = 32;            // B*H
// exp2-domain softmax: fold 1/sqrt(D)*log2(e) into Q once.
constexpr float QSCALE = 0.125f * 1.44269504088896340736f;
constexpr float DEFER_THR = 11.5416f;   // 8 nats in log2 units (T13)

typedef __attribute__((ext_vector_type(8))) short frag8;      // 8 bf16 MFMA operand
typedef __attribute__((ext_vector_type(4))) float f32x4;      // MFMA accumulator
typedef __attribute__((ext_vector_type(4))) short short4v;
typedef __attribute__((ext_vector_type(4))) unsigned int u32x4;

__device__ __forceinline__ short f2bf(float f) {
    unsigned u = __builtin_bit_cast(unsigned, f);
    u += 0x7FFFu + ((u >> 16) & 1u);          // RNE to bf16
    return (short)(u >> 16);
}
__device__ __forceinline__ unsigned pack2(float lo, float hi) {
    return (unsigned)(unsigned short)f2bf(lo) | ((unsigned)(unsigned short)f2bf(hi) << 16);
}
// key k -> LDS row. [k5][k4k3][k2][k1k0] -> [k5][k2][k4k3][k1k0]: QK-tile t reads
// natural rows t*16+c and S^T lands exactly in the PV A-frag key order.
__device__ __forceinline__ int kperm(int kk) {
    return (kk & 0x23) | ((kk & 4) << 2) | ((kk & 0x18) >> 1);
}

#define GLOAD_LDS16(gsrc, ldst)                                          \
    __builtin_amdgcn_global_load_lds(                                    \
        (const __attribute__((address_space(1))) void*)(gsrc),           \
        (__attribute__((address_space(3))) void*)(ldst), 16, 0, 0)

// ============================================================================
// Pre-pass: fp32 K,V -> bf16 LDS-image layout in d_ws (byte-identical to what
// the main kernel's LDS must contain; gload_lds then stages it linearly).
// Kp[bh][blk]: row kperm(key), col d ^ ((row&7)<<3).
// Vp[bh][blk]: row d,          col key ^ ((d&7)<<3)   (V transposed).
// ============================================================================
__global__ __launch_bounds__(256) void prep_kernel(
    const float* __restrict__ kg, const float* __restrict__ vg,
    short* __restrict__ kp, short* __restrict__ vp)
{
    const int n   = blockIdx.x;            // 0..1023 = bh*32 + blk
    const int blk = n & 31;
    const float* ksrc = kg + ((size_t)(n >> 5) * Sseq + blk * 64) * Dh;
    const float* vsrc = vg + ((size_t)(n >> 5) * Sseq + blk * 64) * Dh;
    short* kdst = kp + (size_t)n * 4096;
    short* vdst = vp + (size_t)n * 4096;
    const int tid = threadIdx.x;

    #pragma unroll
    for (int p = 0; p < 4; ++p) {
        const int fe = (tid + p * 256) * 4;
        const float4 x = *(const float4*)(ksrc + fe);
        const int key = fe >> 6, d0 = fe & 63;
        const int srow = kperm(key);
        const int scol = d0 ^ ((srow & 7) << 3);
        short4v y;
        y[0] = f2bf(x.x); y[1] = f2bf(x.y);
        y[2] = f2bf(x.z); y[3] = f2bf(x.w);
        *(short4v*)&kdst[srow * 64 + scol] = y;
    }
    const int vd = tid & 63, vkq = tid >> 6;
    const int vswz = (vd & 7) << 3;
    const float* vcol = vsrc + vkq * 16 * Dh + vd;
    frag8 y0, y1;
    #pragma unroll
    for (int i = 0; i < 8; ++i) { y0[i] = f2bf(vcol[i * Dh]); y1[i] = f2bf(vcol[(i + 8) * Dh]); }
    *(frag8*)&vdst[vd * 64 + ((vkq * 16) ^ vswz)]     = y0;
    *(frag8*)&vdst[vd * 64 + ((vkq * 16 + 8) ^ vswz)] = y1;
}

// ============================================================================
// Main kernel: block-causal flash attention; KV staged via async global_load_lds.
// ============================================================================
__global__ __launch_bounds__(256, 4) void battn_kernel(
    const float* __restrict__ qg, const short* __restrict__ kp,
    const short* __restrict__ vp, float* __restrict__ og)
{
    __shared__ short Klds[2][4096];
    __shared__ short Vlds[2][4096];

    // 1024 WGs. XCD-local heads (4 per XCD) + per-CU qt scrambling for balance:
    // CU slot (xcd, s) gets one WG per layer l with qt = l*8 + ((s>>2)+l)%8.
    const int n   = blockIdx.x;
    const int l   = n >> 8;                    // resident layer 0..3
    const int m   = n & 255;
    const int xcd = m & 7;
    const int s   = m >> 3;                    // 0..31
    const int bh  = xcd * 4 + (s & 3);         // 4 heads per XCD
    const int qt  = (l << 3) | (((s >> 2) + l) & 7);
    const int nb  = qt + 1;                    // visible KV blocks

    const float* qh = qg + (size_t)bh * Sseq * Dh;
    float*       oh = og + (size_t)bh * Sseq * Dh;
    const short* kbase = kp + (size_t)bh * 32 * 4096;
    const short* vbase = vp + (size_t)bh * 32 * 4096;

    const int tid  = threadIdx.x;
    const int lane = tid & 63;
    const int w    = tid >> 6;     // wave 0..3 owns q-rows [w*16, w*16+16)
    const int g    = lane >> 4;
    const int c    = lane & 15;    // this lane's q-row within the wave
    const int swzc = (c & 7) << 3; // read-side XOR swizzle (short units)

    // ---- hoisted LDS fragment offsets (loop-invariant; shared by K and V reads) ----
    int loff[4][2];
    #pragma unroll
    for (int t = 0; t < 4; ++t)
        #pragma unroll
        for (int ks = 0; ks < 2; ++ks)
            loff[t][ks] = (t * 16 + c) * 64 + ((ks * 32 + g * 8) ^ swzc);

    // ---- Q fragment (QK B-operand: lane holds Q[qrow=c][d=ks*32+g*8+j]), exp2-scaled ----
    frag8 qf[2];
    {
        const float* qr = qh + (size_t)(qt * 64 + w * 16 + c) * Dh;
        #pragma unroll
        for (int ks = 0; ks < 2; ++ks) {
            const float4 x0 = *(const float4*)(qr + ks * 32 + g * 8);
            const float4 x1 = *(const float4*)(qr + ks * 32 + g * 8 + 4);
            qf[ks][0] = f2bf(x0.x * QSCALE); qf[ks][1] = f2bf(x0.y * QSCALE);
            qf[ks][2] = f2bf(x0.z * QSCALE); qf[ks][3] = f2bf(x0.w * QSCALE);
            qf[ks][4] = f2bf(x1.x * QSCALE); qf[ks][5] = f2bf(x1.y * QSCALE);
            qf[ks][6] = f2bf(x1.z * QSCALE); qf[ks][7] = f2bf(x1.w * QSCALE);
        }
    }

    // wave w stages 2KB of K and 2KB of V per block (linear dest, pre-swizzled src)
    auto issue_gload = [&](int blk, int buf) {
        const short* ks = kbase + blk * 4096 + w * 1024 + lane * 8;
        const short* vs = vbase + blk * 4096 + w * 1024 + lane * 8;
        GLOAD_LDS16(ks,       &Klds[buf][w * 1024]);
        GLOAD_LDS16(ks + 512, &Klds[buf][w * 1024 + 512]);
        GLOAD_LDS16(vs,       &Vlds[buf][w * 1024]);
        GLOAD_LDS16(vs + 512, &Vlds[buf][w * 1024 + 512]);
    };

    float m_run = -1e30f, l_run = 0.f;
    f32x4 oacc[4];
    #pragma unroll
    for (int t = 0; t < 4; ++t) oacc[t] = f32x4{0, 0, 0, 0};

    // One KV-block step. Swapped MFMA: S^T = K·Q^T, lane (g,c) owns q-row c,
    // keys pre-permuted so exp2 results pack straight into the PV A-frag.
    auto step = [&](int buf) {
        f32x4 s4[4];
        __builtin_amdgcn_s_setprio(1);
        #pragma unroll
        for (int t = 0; t < 4; ++t) {
            f32x4 acc = f32x4{0, 0, 0, 0};
            #pragma unroll
            for (int ks = 0; ks < 2; ++ks) {
                const frag8 kf = *(const frag8*)&Klds[buf][loff[t][ks]];
                acc = __builtin_amdgcn_mfma_f32_16x16x32_bf16(kf, qf[ks], acc, 0, 0, 0);
            }
            s4[t] = acc;
        }
        __builtin_amdgcn_s_setprio(0);

        float pmax = s4[0][0];
        #pragma unroll
        for (int t = 0; t < 4; ++t)
            #pragma unroll
            for (int r = 0; r < 4; ++r) pmax = fmaxf(pmax, s4[t][r]);
        pmax = fmaxf(pmax, __shfl_xor(pmax, 16));
        pmax = fmaxf(pmax, __shfl_xor(pmax, 32));
        if (!__all(pmax <= m_run + DEFER_THR)) {     // T13 defer-max (log2 units)
            const float mn   = fmaxf(m_run, pmax);
            const float corr = __builtin_amdgcn_exp2f(m_run - mn);
            m_run = mn;
            l_run *= corr;
            #pragma unroll
            for (int r = 0; r < 4; ++r) {
                const float cr = __shfl(corr, g * 4 + r);   // O rows are g*4+r
                #pragma unroll
                for (int t = 0; t < 4; ++t) oacc[t][r] *= cr;
            }
        }
        float e[4][4];
        float rs = 0.f;
        #pragma unroll
        for (int t = 0; t < 4; ++t)
            #pragma unroll
            for (int r = 0; r < 4; ++r) {
                e[t][r] = __builtin_amdgcn_exp2f(s4[t][r] - m_run);
                rs += e[t][r];
            }
        rs += __shfl_xor(rs, 16);
        rs += __shfl_xor(rs, 32);
        l_run += rs;

        u32x4 paf[2];
        paf[0] = u32x4{pack2(e[0][0], e[0][1]), pack2(e[0][2], e[0][3]),
                       pack2(e[1][0], e[1][1]), pack2(e[1][2], e[1][3])};
        paf[1] = u32x4{pack2(e[2][0], e[2][1]), pack2(e[2][2], e[2][3]),
                       pack2(e[3][0], e[3][1]), pack2(e[3][2], e[3][3])};
        __builtin_amdgcn_s_setprio(1);
        #pragma unroll
        for (int ks = 0; ks < 2; ++ks) {
            const frag8 pf = __builtin_bit_cast(frag8, paf[ks]);
            #pragma unroll
            for (int t = 0; t < 4; ++t) {
                const frag8 vf = *(const frag8*)&Vlds[buf][loff[t][ks]];
                oacc[t] = __builtin_amdgcn_mfma_f32_16x16x32_bf16(pf, vf, oacc[t], 0, 0, 0);
            }
        }
        __builtin_amdgcn_s_setprio(0);
    };

    // ---- main loop, 2x-unrolled so `buf` is compile-time; loads span barriers ----
    issue_gload(0, 0);
    int sb = 0;
    while (true) {
        __syncthreads();                          // buf0 landed; buf1 readers done
        if (sb + 1 < nb) issue_gload(sb + 1, 1);  // async into buf1 across compute
        step(0);
        if (++sb >= nb) break;

        __syncthreads();
        if (sb + 1 < nb) issue_gload(sb + 1, 0);
        step(1);
        if (++sb >= nb) break;
    }

    // ---- epilogue ----
    const float linv = 1.f / l_run;
    #pragma unroll
    for (int r = 0; r < 4; ++r) {
        const float lr = __shfl(linv, g * 4 + r);
        float* orow = oh + (size_t)(qt * 64 + w * 16 + g * 4 + r) * Dh;
        #pragma unroll
        for (int t = 0; t < 4; ++t) orow[t * 16 + c] = oacc[t][r] * lr;
    }
}

// ============================================================================
// Fallback (round-4 self-converting kernel) if ws_size is too small.
// ============================================================================
__global__ __launch_bounds__(256, 4) void battn_fb(
    const float* __restrict__ qg, const float* __restrict__ kg,
    const float* __restrict__ vg, float* __restrict__ og)
{
    __shared__ short Klds[2][4096];
    __shared__ short Vlds[2][4096];

    const int n   = blockIdx.x;
    const int l   = n >> 8;
    const int m   = n & 255;
    const int xcd = m & 7;
    const int s   = m >> 3;
    const int bh  = xcd * 4 + (s & 3);
    const int qt  = (l << 3) | (((s >> 2) + l) & 7);
    const int nb  = qt + 1;

    const size_t hoff = (size_t)bh * Sseq * Dh;
    const float* qh = qg + hoff;
    const float* kh = kg + hoff;
    const float* vh = vg + hoff;
    float*       oh = og + hoff;

    const int tid  = threadIdx.x;
    const int lane = tid & 63;
    const int w    = tid >> 6;
    const int g    = lane >> 4;
    const int c    = lane & 15;
    const int swzc = (c & 7) << 3;
    const int vd   = tid & 63;
    const int vkq  = tid >> 6;
    const int vswz = (vd & 7) << 3;

    int loff[4][2];
    #pragma unroll
    for (int t = 0; t < 4; ++t)
        #pragma unroll
        for (int ks = 0; ks < 2; ++ks)
            loff[t][ks] = (t * 16 + c) * 64 + ((ks * 32 + g * 8) ^ swzc);

    frag8 qf[2];
    {
        const float* qr = qh + (size_t)(qt * 64 + w * 16 + c) * Dh;
        #pragma unroll
        for (int ks = 0; ks < 2; ++ks) {
            const float4 x0 = *(const float4*)(qr + ks * 32 + g * 8);
            const float4 x1 = *(const float4*)(qr + ks * 32 + g * 8 + 4);
            qf[ks][0] = f2bf(x0.x * QSCALE); qf[ks][1] = f2bf(x0.y * QSCALE);
            qf[ks][2] = f2bf(x0.z * QSCALE); qf[ks][3] = f2bf(x0.w * QSCALE);
            qf[ks][4] = f2bf(x1.x * QSCALE); qf[ks][5] = f2bf(x1.y * QSCALE);
            qf[ks][6] = f2bf(x1.z * QSCALE); qf[ks][7] = f2bf(x1.w * QSCALE);
        }
    }

    float4 kx[4];
    float  vx[16];
    auto issue_loads = [&](int blk) {
        const float4* ksrc = (const float4*)(kh + (size_t)blk * 64 * Dh);
        #pragma unroll
        for (int p = 0; p < 4; ++p) kx[p] = ksrc[tid + p * 256];
        const float* vsrc = vh + ((size_t)blk * 64 + vkq * 16) * Dh + vd;
        #pragma unroll
        for (int i = 0; i < 16; ++i) vx[i] = vsrc[i * Dh];
    };
    auto write_stage = [&](int buf) {
        #pragma unroll
        for (int p = 0; p < 4; ++p) {
            const int fe   = (tid + p * 256) * 4;
            const int key  = fe >> 6;
            const int srow = kperm(key);
            const int scol = (fe & 63) ^ ((srow & 7) << 3);
            short4v y;
            y[0] = f2bf(kx[p].x); y[1] = f2bf(kx[p].y);
            y[2] = f2bf(kx[p].z); y[3] = f2bf(kx[p].w);
            *(short4v*)&Klds[buf][srow * 64 + scol] = y;
        }
        frag8 y0, y1;
        #pragma unroll
        for (int i = 0; i < 8; ++i) { y0[i] = f2bf(vx[i]); y1[i] = f2bf(vx[8 + i]); }
        *(frag8*)&Vlds[buf][vd * 64 + ((vkq * 16) ^ vswz)]     = y0;
        *(frag8*)&Vlds[buf][vd * 64 + ((vkq * 16 + 8) ^ vswz)] = y1;
    };

    float m_run = -1e30f, l_run = 0.f;
    f32x4 oacc[4];
    #pragma unroll
    for (int t = 0; t < 4; ++t) oacc[t] = f32x4{0, 0, 0, 0};

    auto step = [&](int buf) {
        f32x4 s4[4];
        #pragma unroll
        for (int t = 0; t < 4; ++t) {
            f32x4 acc = f32x4{0, 0, 0, 0};
            #pragma unroll
            for (int ks = 0; ks < 2; ++ks) {
                const frag8 kf = *(const frag8*)&Klds[buf][loff[t][ks]];
                acc = __builtin_amdgcn_mfma_f32_16x16x32_bf16(kf, qf[ks], acc, 0, 0, 0);
            }
            s4[t] = acc;
        }
        float pmax = s4[0][0];
        #pragma unroll
        for (int t = 0; t < 4; ++t)
            #pragma unroll
            for (int r = 0; r < 4; ++r) pmax = fmaxf(pmax, s4[t][r]);
        pmax = fmaxf(pmax, __shfl_xor(pmax, 16));
        pmax = fmaxf(pmax, __shfl_xor(pmax, 32));
        if (!__all(pmax <= m_run + DEFER_THR)) {
            const float mn   = fmaxf(m_run, pmax);
            const float corr = __builtin_amdgcn_exp2f(m_run - mn);
            m_run = mn;
            l_run *= corr;
            #pragma unroll
            for (int r = 0; r < 4; ++r) {
                const float cr = __shfl(corr, g * 4 + r);
                #pragma unroll
                for (int t = 0; t < 4; ++t) oacc[t][r] *= cr;
            }
        }
        float e[4][4];
        float rs = 0.f;
        #pragma unroll
        for (int t = 0; t < 4; ++t)
            #pragma unroll
            for (int r = 0; r < 4; ++r) {
                e[t][r] = __builtin_amdgcn_exp2f(s4[t][r] - m_run);
                rs += e[t][r];
            }
        rs += __shfl_xor(rs, 16);
        rs += __shfl_xor(rs, 32);
        l_run += rs;
        u32x4 paf[2];
        paf[0] = u32x4{pack2(e[0][0], e[0][1]), pack2(e[0][2], e[0][3]),
                       pack2(e[1][0], e[1][1]), pack2(e[1][2], e[1][3])};
        paf[1] = u32x4{pack2(e[2][0], e[2][1]), pack2(e[2][2], e[2][3]),
                       pack2(e[3][0], e[3][1]), pack2(e[3][2], e[3][3])};
        #pragma unroll
        for (int ks = 0; ks < 2; ++ks) {
            const frag8 pf = __builtin_bit_cast(frag8, paf[ks]);
            #pragma unroll
            for (int t = 0; t < 4; ++t) {
                const frag8 vf = *(const frag8*)&Vlds[buf][loff[t][ks]];
                oacc[t] = __builtin_amdgcn_mfma_f32_16x16x32_bf16(pf, vf, oacc[t], 0, 0, 0);
            }
        }
    };

    issue_loads(0);
    write_stage(0);
    int sb = 0;
    while (true) {
        __syncthreads();
        if (sb + 1 < nb) issue_loads(sb + 1);
        step(0);
        if (sb + 1 < nb) write_stage(1);
        if (++sb >= nb) break;

        __syncthreads();
        if (sb + 1 < nb) issue_loads(sb + 1);
        step(1);
        if (sb + 1 < nb) write_stage(0);
        if (++sb >= nb) break;
    }

    const float linv = 1.f / l_run;
    #pragma unroll
    for (int r = 0; r < 4; ++r) {
        const float lr = __shfl(linv, g * 4 + r);
        float* orow = oh + (size_t)(qt * 64 + w * 16 + g * 4 + r) * Dh;
        #pragma unroll
        for (int t = 0; t < 4; ++t) orow[t * 16 + c] = oacc[t][r] * lr;
    }
}

} // namespace

extern "C" void kernel_launch(void* const* d_in, const int* in_sizes, int n_in,
                              void* d_out, int out_size, void* d_ws, size_t ws_size,
                              hipStream_t stream) {
    const float* q = (const float*)d_in[0];
    const float* k = (const float*)d_in[1];
    const float* v = (const float*)d_in[2];
    float* out = (float*)d_out;

    const size_t tensor_shorts = (size_t)BH * 32 * 4096;        // 4096 shorts per (bh,blk)
    const size_t need = 2 * tensor_shorts * sizeof(short);      // ~16.8 MB

    if (ws_size >= need) {
        short* kp = (short*)d_ws;
        short* vp = kp + tensor_shorts;
        prep_kernel<<<dim3(BH * 32), dim3(256), 0, stream>>>(k, v, kp, vp);
        battn_kernel<<<dim3(BH * NT), dim3(256), 0, stream>>>(q, kp, vp, out);
    } else {
        battn_fb<<<dim3(BH * NT), dim3(256), 0, stream>>>(q, k, v, out);
    }
}

// Round 6
// 133.322 us; speedup vs baseline: 1.0053x; 1.0053x over previous
//
#include <hip/hip_runtime.h>

namespace {

constexpr int Dh   = 64;
constexpr int Sseq = 2048;
constexpr int NT   = Sseq / 64;     // 32 q-tiles per head
constexpr int BH   = 32;            // B*H
// exp2-domain softmax: fold 1/sqrt(D)*log2(e) into Q once.
constexpr float QSCALE = 0.125f * 1.44269504088896340736f;
constexpr float DEFER_THR = 11.5416f;   // 8 nats in log2 units (T13)

typedef __attribute__((ext_vector_type(8))) short frag8;      // 8 bf16 MFMA operand
typedef __attribute__((ext_vector_type(4))) float f32x4;      // MFMA accumulator
typedef __attribute__((ext_vector_type(4))) short short4v;
typedef __attribute__((ext_vector_type(4))) unsigned int u32x4;

__device__ __forceinline__ short f2bf(float f) {
    unsigned u = __builtin_bit_cast(unsigned, f);
    u += 0x7FFFu + ((u >> 16) & 1u);          // RNE to bf16
    return (short)(u >> 16);
}
// truncating bf16 pack (P in (0,1]: trunc error <= 2^-8 rel, well under budget)
__device__ __forceinline__ unsigned pack2t(float lo, float hi) {
    return (__builtin_bit_cast(unsigned, hi) & 0xFFFF0000u) |
           (__builtin_bit_cast(unsigned, lo) >> 16);
}
// inverse of the key permutation r=[k5][k2][k4k3][k1k0] used so that the
// QK^T D-layout rows land exactly in PV A-frag key order.
__device__ __forceinline__ int kinv(int r) {
    return (r & 0x23) | ((r & 0x10) >> 2) | ((r & 0xC) << 1);
}

// ============================================================================
// Pre-pass: fp32 K,V -> bf16 per-fragment LANE-MAJOR gather images in d_ws.
// Fragment f = ks*4+t (512 shorts): entry for lane l (8 shorts) at f*512+l*8.
//   Kp2[bh][blk] frag(f,l,j) = K[ kinv(t*16 + (l&15)) ][ ks*32 + (l>>4)*8 + j ]
//   Vp2[bh][blk] frag(f,l,j) = V[ ks*32 + (l>>4)*8 + j ][ t*16 + (l&15) ]
// Main kernel then loads each MFMA operand as ONE coalesced global dwordx4.
// ============================================================================
__global__ __launch_bounds__(256) void prep_kernel(
    const float* __restrict__ kg, const float* __restrict__ vg,
    short* __restrict__ kp, short* __restrict__ vp)
{
    const int n   = blockIdx.x;            // 0..1023 = bh*32 + blk
    const int blk = n & 31;
    const float* ksrc = kg + ((size_t)(n >> 5) * Sseq + blk * 64) * Dh;
    const float* vsrc = vg + ((size_t)(n >> 5) * Sseq + blk * 64) * Dh;
    short* kd = kp + (size_t)n * 4096;
    short* vd = vp + (size_t)n * 4096;

    const int tid = threadIdx.x;
    const int f   = tid >> 5;              // fragment 0..7
    const int ks  = f >> 2, t = f & 3;

    #pragma unroll
    for (int e = 0; e < 2; ++e) {
        const int lane = ((tid & 31) << 1) | e;
        const int g = lane >> 4, c = lane & 15;

        // K gather (8 consecutive floats in one K row)
        const int key = kinv(t * 16 + c);
        const float* krow = ksrc + (size_t)key * Dh + ks * 32 + g * 8;
        const float4 k0 = *(const float4*)krow;
        const float4 k1 = *(const float4*)(krow + 4);
        frag8 y;
        y[0] = f2bf(k0.x); y[1] = f2bf(k0.y); y[2] = f2bf(k0.z); y[3] = f2bf(k0.w);
        y[4] = f2bf(k1.x); y[5] = f2bf(k1.y); y[6] = f2bf(k1.z); y[7] = f2bf(k1.w);
        *(frag8*)&kd[f * 512 + lane * 8] = y;

        // V gather (transpose: 8 strided floats down one V column)
        const float* vcol = vsrc + (size_t)(ks * 32 + g * 8) * Dh + t * 16 + c;
        frag8 z;
        #pragma unroll
        for (int j = 0; j < 8; ++j) z[j] = f2bf(vcol[j * Dh]);
        *(frag8*)&vd[f * 512 + lane * 8] = z;
    }
}

// ============================================================================
// Main kernel: block-causal flash attention. NO LDS, NO barriers.
// All MFMA operands loaded directly from L2-resident Kp2/Vp2 (one coalesced
// dwordx4 each); software-pipelined so waits are counted vmcnt, never drains.
// block = 128 (2 waves); each wave owns 32 q-rows (2 row-groups of 16).
// ============================================================================
__global__ __launch_bounds__(128, 2) void battn_kernel(
    const float* __restrict__ qg, const short* __restrict__ kp,
    const short* __restrict__ vp, float* __restrict__ og)
{
    // 1024 WGs. XCD-local heads (4 per XCD); per-CU qt spread via +2l stride
    // (resident qts {k,k+2,k+4,k+6} mod 8 ladder -> per-CU work within ±3%).
    const int n   = blockIdx.x;
    const int l   = n >> 8;                    // resident layer 0..3
    const int m   = n & 255;
    const int xcd = m & 7;
    const int s   = m >> 3;                    // 0..31
    const int bh  = xcd * 4 + (s & 3);         // 4 heads per XCD
    const int qt  = (l << 3) | (((s >> 2) + 2 * l) & 7);
    const int nb  = qt + 1;                    // visible KV blocks

    const float* qh = qg + (size_t)bh * Sseq * Dh;
    float*       oh = og + (size_t)bh * Sseq * Dh;
    const short* kb = kp + (size_t)bh * 32 * 4096;
    const short* vb = vp + (size_t)bh * 32 * 4096;

    const int tid  = threadIdx.x;
    const int lane = tid & 63;
    const int w    = tid >> 6;     // wave 0..1: q-rows [w*32, w*32+32)
    const int g    = lane >> 4;
    const int c    = lane & 15;
    const int loff = lane * 8;     // lane entry offset within a fragment (shorts)

    // ---- Q fragments (QK B-operand: lane holds Q[row=w*32+rg*16+c][d]) ----
    frag8 qf[2][2];
    #pragma unroll
    for (int rg = 0; rg < 2; ++rg) {
        const float* qr = qh + (size_t)(qt * 64 + w * 32 + rg * 16 + c) * Dh;
        #pragma unroll
        for (int ks = 0; ks < 2; ++ks) {
            const float4 x0 = *(const float4*)(qr + ks * 32 + g * 8);
            const float4 x1 = *(const float4*)(qr + ks * 32 + g * 8 + 4);
            qf[rg][ks][0] = f2bf(x0.x * QSCALE); qf[rg][ks][1] = f2bf(x0.y * QSCALE);
            qf[rg][ks][2] = f2bf(x0.z * QSCALE); qf[rg][ks][3] = f2bf(x0.w * QSCALE);
            qf[rg][ks][4] = f2bf(x1.x * QSCALE); qf[rg][ks][5] = f2bf(x1.y * QSCALE);
            qf[rg][ks][6] = f2bf(x1.z * QSCALE); qf[rg][ks][7] = f2bf(x1.w * QSCALE);
        }
    }

    float m_run[2] = {-1e30f, -1e30f};
    float l_run[2] = {0.f, 0.f};
    f32x4 oacc[2][4];
    #pragma unroll
    for (int rg = 0; rg < 2; ++rg)
        #pragma unroll
        for (int t = 0; t < 4; ++t) oacc[rg][t] = f32x4{0.f, 0.f, 0.f, 0.f};

    frag8 kf[8], vf[8];
    // prologue: K fragments of block 0
    #pragma unroll
    for (int f = 0; f < 8; ++f) kf[f] = *(const frag8*)&kb[f * 512 + loff];

    int j = 0;
    while (true) {
        // ---- issue V(j): consumed at PV, covered by QK+softmax ----
        {
            const short* vblk = vb + (size_t)j * 4096;
            #pragma unroll
            for (int f = 0; f < 8; ++f) vf[f] = *(const frag8*)&vblk[f * 512 + loff];
        }

        // ---- S^T = K·Q^T (kf ready from previous iteration's prefetch) ----
        f32x4 s4[2][4];
        __builtin_amdgcn_s_setprio(1);
        #pragma unroll
        for (int rg = 0; rg < 2; ++rg)
            #pragma unroll
            for (int t = 0; t < 4; ++t) {
                f32x4 acc = f32x4{0.f, 0.f, 0.f, 0.f};
                acc = __builtin_amdgcn_mfma_f32_16x16x32_bf16(kf[t],     qf[rg][0], acc, 0, 0, 0);
                acc = __builtin_amdgcn_mfma_f32_16x16x32_bf16(kf[4 + t], qf[rg][1], acc, 0, 0, 0);
                s4[rg][t] = acc;
            }
        __builtin_amdgcn_s_setprio(0);

        // ---- issue K(j+1): consumed next iteration, covered by softmax+PV ----
        {
            const int jn = (j + 1 < nb) ? (j + 1) : j;
            const short* kblk = kb + (size_t)jn * 4096;
            #pragma unroll
            for (int f = 0; f < 8; ++f) kf[f] = *(const frag8*)&kblk[f * 512 + loff];
        }

        // ---- online softmax per row-group (lane owns q-row c; keys pre-permuted
        //      so exp2 results pack straight into the PV A-fragment) ----
        u32x4 paf[2][2];
        #pragma unroll
        for (int rg = 0; rg < 2; ++rg) {
            float pmax = s4[rg][0][0];
            #pragma unroll
            for (int t = 0; t < 4; ++t)
                #pragma unroll
                for (int r = 0; r < 4; ++r) pmax = fmaxf(pmax, s4[rg][t][r]);
            pmax = fmaxf(pmax, __shfl_xor(pmax, 16));
            pmax = fmaxf(pmax, __shfl_xor(pmax, 32));
            if (!__all(pmax <= m_run[rg] + DEFER_THR)) {   // T13 defer-max
                const float mn   = fmaxf(m_run[rg], pmax);
                const float corr = __builtin_amdgcn_exp2f(m_run[rg] - mn);
                m_run[rg] = mn;
                l_run[rg] *= corr;
                #pragma unroll
                for (int r = 0; r < 4; ++r) {
                    const float cr = __shfl(corr, g * 4 + r);   // O rows are g*4+r
                    #pragma unroll
                    for (int t = 0; t < 4; ++t) oacc[rg][t][r] *= cr;
                }
            }
            float e[4][4];
            float rs = 0.f;
            #pragma unroll
            for (int t = 0; t < 4; ++t)
                #pragma unroll
                for (int r = 0; r < 4; ++r) {
                    e[t][r] = __builtin_amdgcn_exp2f(s4[rg][t][r] - m_run[rg]);
                    rs += e[t][r];
                }
            rs += __shfl_xor(rs, 16);
            rs += __shfl_xor(rs, 32);
            l_run[rg] += rs;
            paf[rg][0] = u32x4{pack2t(e[0][0], e[0][1]), pack2t(e[0][2], e[0][3]),
                               pack2t(e[1][0], e[1][1]), pack2t(e[1][2], e[1][3])};
            paf[rg][1] = u32x4{pack2t(e[2][0], e[2][1]), pack2t(e[2][2], e[2][3]),
                               pack2t(e[3][0], e[3][1]), pack2t(e[3][2], e[3][3])};
        }

        // ---- O += P·V (vf landed long ago; counted wait, kf still in flight) ----
        __builtin_amdgcn_s_setprio(1);
        #pragma unroll
        for (int rg = 0; rg < 2; ++rg)
            #pragma unroll
            for (int ks = 0; ks < 2; ++ks) {
                const frag8 pf = __builtin_bit_cast(frag8, paf[rg][ks]);
                #pragma unroll
                for (int t = 0; t < 4; ++t)
                    oacc[rg][t] = __builtin_amdgcn_mfma_f32_16x16x32_bf16(
                        pf, vf[ks * 4 + t], oacc[rg][t], 0, 0, 0);
            }
        __builtin_amdgcn_s_setprio(0);

        if (++j >= nb) break;
    }

    // ---- epilogue ----
    #pragma unroll
    for (int rg = 0; rg < 2; ++rg) {
        const float linv = 1.f / l_run[rg];
        #pragma unroll
        for (int r = 0; r < 4; ++r) {
            const float lr = __shfl(linv, g * 4 + r);
            float* orow = oh + (size_t)(qt * 64 + w * 32 + rg * 16 + g * 4 + r) * Dh;
            #pragma unroll
            for (int t = 0; t < 4; ++t) orow[t * 16 + c] = oacc[rg][t][r] * lr;
        }
    }
}

// ============================================================================
// Fallback (round-5 self-converting LDS kernel) if ws_size is too small.
// ============================================================================
constexpr float SCALE_FB = QSCALE;

__device__ __forceinline__ unsigned pack2(float lo, float hi) {
    return (unsigned)(unsigned short)f2bf(lo) | ((unsigned)(unsigned short)f2bf(hi) << 16);
}
__device__ __forceinline__ int kperm(int kk) {
    return (kk & 0x23) | ((kk & 4) << 2) | ((kk & 0x18) >> 1);
}

__global__ __launch_bounds__(256, 4) void battn_fb(
    const float* __restrict__ qg, const float* __restrict__ kg,
    const float* __restrict__ vg, float* __restrict__ og)
{
    __shared__ short Klds[2][4096];
    __shared__ short Vlds[2][4096];

    const int n   = blockIdx.x;
    const int l   = n >> 8;
    const int m   = n & 255;
    const int xcd = m & 7;
    const int s   = m >> 3;
    const int bh  = xcd * 4 + (s & 3);
    const int qt  = (l << 3) | (((s >> 2) + l) & 7);
    const int nb  = qt + 1;

    const size_t hoff = (size_t)bh * Sseq * Dh;
    const float* qh = qg + hoff;
    const float* kh = kg + hoff;
    const float* vh = vg + hoff;
    float*       oh = og + hoff;

    const int tid  = threadIdx.x;
    const int lane = tid & 63;
    const int w    = tid >> 6;
    const int g    = lane >> 4;
    const int c    = lane & 15;
    const int swzc = (c & 7) << 3;
    const int vd   = tid & 63;
    const int vkq  = tid >> 6;
    const int vswz = (vd & 7) << 3;

    int loff2[4][2];
    #pragma unroll
    for (int t = 0; t < 4; ++t)
        #pragma unroll
        for (int ks = 0; ks < 2; ++ks)
            loff2[t][ks] = (t * 16 + c) * 64 + ((ks * 32 + g * 8) ^ swzc);

    frag8 qf[2];
    {
        const float* qr = qh + (size_t)(qt * 64 + w * 16 + c) * Dh;
        #pragma unroll
        for (int ks = 0; ks < 2; ++ks) {
            const float4 x0 = *(const float4*)(qr + ks * 32 + g * 8);
            const float4 x1 = *(const float4*)(qr + ks * 32 + g * 8 + 4);
            qf[ks][0] = f2bf(x0.x * SCALE_FB); qf[ks][1] = f2bf(x0.y * SCALE_FB);
            qf[ks][2] = f2bf(x0.z * SCALE_FB); qf[ks][3] = f2bf(x0.w * SCALE_FB);
            qf[ks][4] = f2bf(x1.x * SCALE_FB); qf[ks][5] = f2bf(x1.y * SCALE_FB);
            qf[ks][6] = f2bf(x1.z * SCALE_FB); qf[ks][7] = f2bf(x1.w * SCALE_FB);
        }
    }

    float4 kx[4];
    float  vx[16];
    auto issue_loads = [&](int blk) {
        const float4* ksrc = (const float4*)(kh + (size_t)blk * 64 * Dh);
        #pragma unroll
        for (int p = 0; p < 4; ++p) kx[p] = ksrc[tid + p * 256];
        const float* vsrc = vh + ((size_t)blk * 64 + vkq * 16) * Dh + vd;
        #pragma unroll
        for (int i = 0; i < 16; ++i) vx[i] = vsrc[i * Dh];
    };
    auto write_stage = [&](int buf) {
        #pragma unroll
        for (int p = 0; p < 4; ++p) {
            const int fe   = (tid + p * 256) * 4;
            const int key  = fe >> 6;
            const int srow = kperm(key);
            const int scol = (fe & 63) ^ ((srow & 7) << 3);
            short4v y;
            y[0] = f2bf(kx[p].x); y[1] = f2bf(kx[p].y);
            y[2] = f2bf(kx[p].z); y[3] = f2bf(kx[p].w);
            *(short4v*)&Klds[buf][srow * 64 + scol] = y;
        }
        frag8 y0, y1;
        #pragma unroll
        for (int i = 0; i < 8; ++i) { y0[i] = f2bf(vx[i]); y1[i] = f2bf(vx[8 + i]); }
        *(frag8*)&Vlds[buf][vd * 64 + ((vkq * 16) ^ vswz)]     = y0;
        *(frag8*)&Vlds[buf][vd * 64 + ((vkq * 16 + 8) ^ vswz)] = y1;
    };

    float m_run = -1e30f, l_run = 0.f;
    f32x4 oacc[4];
    #pragma unroll
    for (int t = 0; t < 4; ++t) oacc[t] = f32x4{0, 0, 0, 0};

    auto step = [&](int buf) {
        f32x4 s4[4];
        #pragma unroll
        for (int t = 0; t < 4; ++t) {
            f32x4 acc = f32x4{0, 0, 0, 0};
            #pragma unroll
            for (int ks = 0; ks < 2; ++ks) {
                const frag8 kfr = *(const frag8*)&Klds[buf][loff2[t][ks]];
                acc = __builtin_amdgcn_mfma_f32_16x16x32_bf16(kfr, qf[ks], acc, 0, 0, 0);
            }
            s4[t] = acc;
        }
        float pmax = s4[0][0];
        #pragma unroll
        for (int t = 0; t < 4; ++t)
            #pragma unroll
            for (int r = 0; r < 4; ++r) pmax = fmaxf(pmax, s4[t][r]);
        pmax = fmaxf(pmax, __shfl_xor(pmax, 16));
        pmax = fmaxf(pmax, __shfl_xor(pmax, 32));
        if (!__all(pmax <= m_run + DEFER_THR)) {
            const float mn   = fmaxf(m_run, pmax);
            const float corr = __builtin_amdgcn_exp2f(m_run - mn);
            m_run = mn;
            l_run *= corr;
            #pragma unroll
            for (int r = 0; r < 4; ++r) {
                const float cr = __shfl(corr, g * 4 + r);
                #pragma unroll
                for (int t = 0; t < 4; ++t) oacc[t][r] *= cr;
            }
        }
        float e[4][4];
        float rs = 0.f;
        #pragma unroll
        for (int t = 0; t < 4; ++t)
            #pragma unroll
            for (int r = 0; r < 4; ++r) {
                e[t][r] = __builtin_amdgcn_exp2f(s4[t][r] - m_run);
                rs += e[t][r];
            }
        rs += __shfl_xor(rs, 16);
        rs += __shfl_xor(rs, 32);
        l_run += rs;
        u32x4 paf[2];
        paf[0] = u32x4{pack2(e[0][0], e[0][1]), pack2(e[0][2], e[0][3]),
                       pack2(e[1][0], e[1][1]), pack2(e[1][2], e[1][3])};
        paf[1] = u32x4{pack2(e[2][0], e[2][1]), pack2(e[2][2], e[2][3]),
                       pack2(e[3][0], e[3][1]), pack2(e[3][2], e[3][3])};
        #pragma unroll
        for (int ks = 0; ks < 2; ++ks) {
            const frag8 pf = __builtin_bit_cast(frag8, paf[ks]);
            #pragma unroll
            for (int t = 0; t < 4; ++t) {
                const frag8 vfr = *(const frag8*)&Vlds[buf][loff2[t][ks]];
                oacc[t] = __builtin_amdgcn_mfma_f32_16x16x32_bf16(pf, vfr, oacc[t], 0, 0, 0);
            }
        }
    };

    issue_loads(0);
    write_stage(0);
    int sb = 0;
    while (true) {
        __syncthreads();
        if (sb + 1 < nb) issue_loads(sb + 1);
        step(0);
        if (sb + 1 < nb) write_stage(1);
        if (++sb >= nb) break;

        __syncthreads();
        if (sb + 1 < nb) issue_loads(sb + 1);
        step(1);
        if (sb + 1 < nb) write_stage(0);
        if (++sb >= nb) break;
    }

    const float linv = 1.f / l_run;
    #pragma unroll
    for (int r = 0; r < 4; ++r) {
        const float lr = __shfl(linv, g * 4 + r);
        float* orow = oh + (size_t)(qt * 64 + w * 16 + g * 4 + r) * Dh;
        #pragma unroll
        for (int t = 0; t < 4; ++t) orow[t * 16 + c] = oacc[t][r] * lr;
    }
}

} // namespace

extern "C" void kernel_launch(void* const* d_in, const int* in_sizes, int n_in,
                              void* d_out, int out_size, void* d_ws, size_t ws_size,
                              hipStream_t stream) {
    const float* q = (const float*)d_in[0];
    const float* k = (const float*)d_in[1];
    const float* v = (const float*)d_in[2];
    float* out = (float*)d_out;

    const size_t tensor_shorts = (size_t)BH * 32 * 4096;        // 4096 shorts per (bh,blk)
    const size_t need = 2 * tensor_shorts * sizeof(short);      // ~16.8 MB

    if (ws_size >= need) {
        short* kp = (short*)d_ws;
        short* vp = kp + tensor_shorts;
        prep_kernel<<<dim3(BH * 32), dim3(256), 0, stream>>>(k, v, kp, vp);
        battn_kernel<<<dim3(BH * NT), dim3(128), 0, stream>>>(q, kp, vp, out);
    } else {
        battn_fb<<<dim3(BH * NT), dim3(256), 0, stream>>>(q, k, v, out);
    }
}

// Round 7
// 123.088 us; speedup vs baseline: 1.0889x; 1.0831x over previous
//
#include <hip/hip_runtime.h>

namespace {

constexpr int Dh   = 64;
constexpr int Sseq = 2048;
constexpr int NT   = Sseq / 64;     // 32 q-tiles per head
constexpr int BH   = 32;            // B*H
// exp2-domain softmax: fold 1/sqrt(D)*log2(e) into Q once.
constexpr float QSCALE = 0.125f * 1.44269504088896340736f;
// static softmax shift (log2 units). Softmax is shift-invariant; this only
// needs to keep 2^(s'-M) inside fp32/bf16 exponent range: |s'| <= ~92 worst
// case (||q||*||k||/8 * log2e), range is +-126. No online max needed.
constexpr float M_STATIC = 24.0f;
constexpr float DEFER_THR = 11.5416f;   // fallback kernel only

typedef __attribute__((ext_vector_type(8))) short frag8;      // 8 bf16 MFMA operand
typedef __attribute__((ext_vector_type(4))) float f32x4;      // MFMA accumulator
typedef __attribute__((ext_vector_type(4))) short short4v;
typedef __attribute__((ext_vector_type(4))) unsigned int u32x4;

__device__ __forceinline__ short f2bf(float f) {
    unsigned u = __builtin_bit_cast(unsigned, f);
    u += 0x7FFFu + ((u >> 16) & 1u);          // RNE to bf16
    return (short)(u >> 16);
}
// truncating bf16 pack of two fp32 via one v_perm_b32
__device__ __forceinline__ unsigned pack2t(float lo, float hi) {
    return __builtin_amdgcn_perm(__builtin_bit_cast(unsigned, hi),
                                 __builtin_bit_cast(unsigned, lo),
                                 0x07060302u);
}
// inverse of the key permutation r=[k5][k2][k4k3][k1k0] used so that the
// QK^T D-layout rows land exactly in PV A-frag key order.
__device__ __forceinline__ int kinv(int r) {
    return (r & 0x23) | ((r & 0x10) >> 2) | ((r & 0xC) << 1);
}

// ============================================================================
// Pre-pass: fp32 K,V -> bf16 per-fragment LANE-MAJOR gather images in d_ws.
// Fragment f = ks*4+t (512 shorts): entry for lane l (8 shorts) at f*512+l*8.
//   Kp2[bh][blk] frag(f,l,j) = K[ kinv(t*16 + (l&15)) ][ ks*32 + (l>>4)*8 + j ]
//   Vp2[bh][blk] frag(f,l,j) = V[ ks*32 + (l>>4)*8 + j ][ t*16 + (l&15) ]
// Main kernel loads each MFMA operand as ONE coalesced global dwordx4.
// ============================================================================
__global__ __launch_bounds__(256) void prep_kernel(
    const float* __restrict__ kg, const float* __restrict__ vg,
    short* __restrict__ kp, short* __restrict__ vp)
{
    const int n   = blockIdx.x;            // 0..1023 = bh*32 + blk
    const int blk = n & 31;
    const float* ksrc = kg + ((size_t)(n >> 5) * Sseq + blk * 64) * Dh;
    const float* vsrc = vg + ((size_t)(n >> 5) * Sseq + blk * 64) * Dh;
    short* kd = kp + (size_t)n * 4096;
    short* vd = vp + (size_t)n * 4096;

    const int tid = threadIdx.x;
    const int f   = tid >> 5;              // fragment 0..7
    const int ks  = f >> 2, t = f & 3;

    #pragma unroll
    for (int e = 0; e < 2; ++e) {
        const int lane = ((tid & 31) << 1) | e;
        const int g = lane >> 4, c = lane & 15;

        // K gather (8 consecutive floats in one K row)
        const int key = kinv(t * 16 + c);
        const float* krow = ksrc + (size_t)key * Dh + ks * 32 + g * 8;
        const float4 k0 = *(const float4*)krow;
        const float4 k1 = *(const float4*)(krow + 4);
        frag8 y;
        y[0] = f2bf(k0.x); y[1] = f2bf(k0.y); y[2] = f2bf(k0.z); y[3] = f2bf(k0.w);
        y[4] = f2bf(k1.x); y[5] = f2bf(k1.y); y[6] = f2bf(k1.z); y[7] = f2bf(k1.w);
        *(frag8*)&kd[f * 512 + lane * 8] = y;

        // V gather (transpose: 8 strided floats down one V column)
        const float* vcol = vsrc + (size_t)(ks * 32 + g * 8) * Dh + t * 16 + c;
        frag8 z;
        #pragma unroll
        for (int j = 0; j < 8; ++j) z[j] = f2bf(vcol[j * Dh]);
        *(frag8*)&vd[f * 512 + lane * 8] = z;
    }
}

// ============================================================================
// Main kernel: block-causal flash attention, static-shift softmax.
// No LDS, no barriers, no cross-lane ops in the hot loop. One wave per block
// (32 q-rows); counted-vmcnt software pipeline on K/V fragment loads.
// ============================================================================
__global__ __launch_bounds__(64, 2) void battn_kernel(
    const float* __restrict__ qg, const short* __restrict__ kp,
    const short* __restrict__ vp, float* __restrict__ og)
{
    // 2048 blocks. xcd = n&7 matches round-robin dispatch -> 4 heads per XCD.
    // l-scramble spreads qt sizes across the 8 resident blocks of each CU.
    const int n    = blockIdx.x;
    const int xcd  = n & 7;
    const int u    = n >> 3;                   // 0..255
    const int half = u & 1;                    // 32-row half of the 64-row tile
    const int uu   = u >> 1;                   // 0..127
    const int bh   = xcd * 4 + (uu & 3);       // 4 heads per XCD
    const int l    = uu >> 5;                  // 0..3
    const int ss   = (uu >> 2) & 7;
    const int qt   = (l << 3) | ((ss + 2 * l) & 7);
    const int nb   = qt + 1;                   // visible KV blocks

    const float* qh = qg + (size_t)bh * Sseq * Dh;
    float*       oh = og + (size_t)bh * Sseq * Dh;

    const int lane = threadIdx.x & 63;
    const int g    = lane >> 4;
    const int c    = lane & 15;
    const int loff = lane * 8;     // lane entry offset within a fragment (shorts)

    const short* kq = kp + (size_t)bh * 32 * 4096 + loff;
    const short* vq = vp + (size_t)bh * 32 * 4096 + loff;

    // ---- Q fragments (QK B-operand: lane holds Q[row=half*32+rg*16+c][d]) ----
    frag8 qf[2][2];
    #pragma unroll
    for (int rg = 0; rg < 2; ++rg) {
        const float* qr = qh + (size_t)(qt * 64 + half * 32 + rg * 16 + c) * Dh;
        #pragma unroll
        for (int ks = 0; ks < 2; ++ks) {
            const float4 x0 = *(const float4*)(qr + ks * 32 + g * 8);
            const float4 x1 = *(const float4*)(qr + ks * 32 + g * 8 + 4);
            qf[rg][ks][0] = f2bf(x0.x * QSCALE); qf[rg][ks][1] = f2bf(x0.y * QSCALE);
            qf[rg][ks][2] = f2bf(x0.z * QSCALE); qf[rg][ks][3] = f2bf(x0.w * QSCALE);
            qf[rg][ks][4] = f2bf(x1.x * QSCALE); qf[rg][ks][5] = f2bf(x1.y * QSCALE);
            qf[rg][ks][6] = f2bf(x1.z * QSCALE); qf[rg][ks][7] = f2bf(x1.w * QSCALE);
        }
    }

    float l_part[2] = {0.f, 0.f};   // per-lane partial denominators (row c, this g-group's keys)
    f32x4 oacc[2][4];
    #pragma unroll
    for (int rg = 0; rg < 2; ++rg)
        #pragma unroll
        for (int t = 0; t < 4; ++t) oacc[rg][t] = f32x4{0.f, 0.f, 0.f, 0.f};

    frag8 kf[8], vf[8];
    #pragma unroll
    for (int f = 0; f < 8; ++f) kf[f] = *(const frag8*)&kq[f * 512];
    #pragma unroll
    for (int f = 0; f < 8; ++f) vf[f] = *(const frag8*)&vq[f * 512];

    int j = 0;
    while (true) {
        // ---- S^T = K·Q^T (kf prefetched; counted wait keeps vf in flight) ----
        f32x4 s4[2][4];
        __builtin_amdgcn_s_setprio(1);
        #pragma unroll
        for (int rg = 0; rg < 2; ++rg)
            #pragma unroll
            for (int t = 0; t < 4; ++t) {
                f32x4 acc = f32x4{0.f, 0.f, 0.f, 0.f};
                acc = __builtin_amdgcn_mfma_f32_16x16x32_bf16(kf[t],     qf[rg][0], acc, 0, 0, 0);
                acc = __builtin_amdgcn_mfma_f32_16x16x32_bf16(kf[4 + t], qf[rg][1], acc, 0, 0, 0);
                s4[rg][t] = acc;
            }
        __builtin_amdgcn_s_setprio(0);

        // ---- prefetch K(j+1): covered by exp + PV ----
        kq += 4096;
        if (j + 1 < nb) {
            #pragma unroll
            for (int f = 0; f < 8; ++f) kf[f] = *(const frag8*)&kq[f * 512];
        }

        // ---- static-shift softmax: pure per-lane exp2 + accumulate + pack ----
        u32x4 paf[2][2];
        #pragma unroll
        for (int rg = 0; rg < 2; ++rg) {
            float e[4][4];
            #pragma unroll
            for (int t = 0; t < 4; ++t)
                #pragma unroll
                for (int r = 0; r < 4; ++r)
                    e[t][r] = __builtin_amdgcn_exp2f(s4[rg][t][r] - M_STATIC);
            float s01 = 0.f, s23 = 0.f;
            #pragma unroll
            for (int r = 0; r < 4; ++r) { s01 += e[0][r] + e[1][r]; s23 += e[2][r] + e[3][r]; }
            l_part[rg] += s01 + s23;
            paf[rg][0] = u32x4{pack2t(e[0][0], e[0][1]), pack2t(e[0][2], e[0][3]),
                               pack2t(e[1][0], e[1][1]), pack2t(e[1][2], e[1][3])};
            paf[rg][1] = u32x4{pack2t(e[2][0], e[2][1]), pack2t(e[2][2], e[2][3]),
                               pack2t(e[3][0], e[3][1]), pack2t(e[3][2], e[3][3])};
        }

        // ---- O += P·V (vf landed; kf(j+1) stays in flight) ----
        __builtin_amdgcn_s_setprio(1);
        #pragma unroll
        for (int rg = 0; rg < 2; ++rg)
            #pragma unroll
            for (int ks = 0; ks < 2; ++ks) {
                const frag8 pf = __builtin_bit_cast(frag8, paf[rg][ks]);
                #pragma unroll
                for (int t = 0; t < 4; ++t)
                    oacc[rg][t] = __builtin_amdgcn_mfma_f32_16x16x32_bf16(
                        pf, vf[ks * 4 + t], oacc[rg][t], 0, 0, 0);
            }
        __builtin_amdgcn_s_setprio(0);

        // ---- prefetch V(j+1): covered by next QK + exp ----
        vq += 4096;
        if (j + 1 < nb) {
            #pragma unroll
            for (int f = 0; f < 8; ++f) vf[f] = *(const frag8*)&vq[f * 512];
        }

        if (++j >= nb) break;
    }

    // ---- epilogue: reduce denominators once, normalize, store ----
    #pragma unroll
    for (int rg = 0; rg < 2; ++rg) {
        float lsum = l_part[rg];
        lsum += __shfl_xor(lsum, 16);
        lsum += __shfl_xor(lsum, 32);
        const float linv = 1.f / lsum;
        #pragma unroll
        for (int r = 0; r < 4; ++r) {
            const float lr = __shfl(linv, g * 4 + r);   // lane g*4+r holds row g*4+r
            float* orow = oh + (size_t)(qt * 64 + half * 32 + rg * 16 + g * 4 + r) * Dh;
            #pragma unroll
            for (int t = 0; t < 4; ++t) orow[t * 16 + c] = oacc[rg][t][r] * lr;
        }
    }
}

// ============================================================================
// Fallback (round-6-style self-converting LDS kernel) if ws_size is too small.
// ============================================================================
__device__ __forceinline__ unsigned pack2(float lo, float hi) {
    return (unsigned)(unsigned short)f2bf(lo) | ((unsigned)(unsigned short)f2bf(hi) << 16);
}
__device__ __forceinline__ int kperm(int kk) {
    return (kk & 0x23) | ((kk & 4) << 2) | ((kk & 0x18) >> 1);
}

__global__ __launch_bounds__(256, 4) void battn_fb(
    const float* __restrict__ qg, const float* __restrict__ kg,
    const float* __restrict__ vg, float* __restrict__ og)
{
    __shared__ short Klds[2][4096];
    __shared__ short Vlds[2][4096];

    const int n   = blockIdx.x;
    const int l   = n >> 8;
    const int m   = n & 255;
    const int xcd = m & 7;
    const int s   = m >> 3;
    const int bh  = xcd * 4 + (s & 3);
    const int qt  = (l << 3) | (((s >> 2) + l) & 7);
    const int nb  = qt + 1;

    const size_t hoff = (size_t)bh * Sseq * Dh;
    const float* qh = qg + hoff;
    const float* kh = kg + hoff;
    const float* vh = vg + hoff;
    float*       oh = og + hoff;

    const int tid  = threadIdx.x;
    const int lane = tid & 63;
    const int w    = tid >> 6;
    const int g    = lane >> 4;
    const int c    = lane & 15;
    const int swzc = (c & 7) << 3;
    const int vd   = tid & 63;
    const int vkq  = tid >> 6;
    const int vswz = (vd & 7) << 3;

    int loff2[4][2];
    #pragma unroll
    for (int t = 0; t < 4; ++t)
        #pragma unroll
        for (int ks = 0; ks < 2; ++ks)
            loff2[t][ks] = (t * 16 + c) * 64 + ((ks * 32 + g * 8) ^ swzc);

    frag8 qf[2];
    {
        const float* qr = qh + (size_t)(qt * 64 + w * 16 + c) * Dh;
        #pragma unroll
        for (int ks = 0; ks < 2; ++ks) {
            const float4 x0 = *(const float4*)(qr + ks * 32 + g * 8);
            const float4 x1 = *(const float4*)(qr + ks * 32 + g * 8 + 4);
            qf[ks][0] = f2bf(x0.x * QSCALE); qf[ks][1] = f2bf(x0.y * QSCALE);
            qf[ks][2] = f2bf(x0.z * QSCALE); qf[ks][3] = f2bf(x0.w * QSCALE);
            qf[ks][4] = f2bf(x1.x * QSCALE); qf[ks][5] = f2bf(x1.y * QSCALE);
            qf[ks][6] = f2bf(x1.z * QSCALE); qf[ks][7] = f2bf(x1.w * QSCALE);
        }
    }

    float4 kx[4];
    float  vx[16];
    auto issue_loads = [&](int blk) {
        const float4* ksrc = (const float4*)(kh + (size_t)blk * 64 * Dh);
        #pragma unroll
        for (int p = 0; p < 4; ++p) kx[p] = ksrc[tid + p * 256];
        const float* vsrc = vh + ((size_t)blk * 64 + vkq * 16) * Dh + vd;
        #pragma unroll
        for (int i = 0; i < 16; ++i) vx[i] = vsrc[i * Dh];
    };
    auto write_stage = [&](int buf) {
        #pragma unroll
        for (int p = 0; p < 4; ++p) {
            const int fe   = (tid + p * 256) * 4;
            const int key  = fe >> 6;
            const int srow = kperm(key);
            const int scol = (fe & 63) ^ ((srow & 7) << 3);
            short4v y;
            y[0] = f2bf(kx[p].x); y[1] = f2bf(kx[p].y);
            y[2] = f2bf(kx[p].z); y[3] = f2bf(kx[p].w);
            *(short4v*)&Klds[buf][srow * 64 + scol] = y;
        }
        frag8 y0, y1;
        #pragma unroll
        for (int i = 0; i < 8; ++i) { y0[i] = f2bf(vx[i]); y1[i] = f2bf(vx[8 + i]); }
        *(frag8*)&Vlds[buf][vd * 64 + ((vkq * 16) ^ vswz)]     = y0;
        *(frag8*)&Vlds[buf][vd * 64 + ((vkq * 16 + 8) ^ vswz)] = y1;
    };

    float m_run = -1e30f, l_run = 0.f;
    f32x4 oacc[4];
    #pragma unroll
    for (int t = 0; t < 4; ++t) oacc[t] = f32x4{0, 0, 0, 0};

    auto step = [&](int buf) {
        f32x4 s4[4];
        #pragma unroll
        for (int t = 0; t < 4; ++t) {
            f32x4 acc = f32x4{0, 0, 0, 0};
            #pragma unroll
            for (int ks = 0; ks < 2; ++ks) {
                const frag8 kfr = *(const frag8*)&Klds[buf][loff2[t][ks]];
                acc = __builtin_amdgcn_mfma_f32_16x16x32_bf16(kfr, qf[ks], acc, 0, 0, 0);
            }
            s4[t] = acc;
        }
        float pmax = s4[0][0];
        #pragma unroll
        for (int t = 0; t < 4; ++t)
            #pragma unroll
            for (int r = 0; r < 4; ++r) pmax = fmaxf(pmax, s4[t][r]);
        pmax = fmaxf(pmax, __shfl_xor(pmax, 16));
        pmax = fmaxf(pmax, __shfl_xor(pmax, 32));
        if (!__all(pmax <= m_run + DEFER_THR)) {
            const float mn   = fmaxf(m_run, pmax);
            const float corr = __builtin_amdgcn_exp2f(m_run - mn);
            m_run = mn;
            l_run *= corr;
            #pragma unroll
            for (int r = 0; r < 4; ++r) {
                const float cr = __shfl(corr, g * 4 + r);
                #pragma unroll
                for (int t = 0; t < 4; ++t) oacc[t][r] *= cr;
            }
        }
        float e[4][4];
        float rs = 0.f;
        #pragma unroll
        for (int t = 0; t < 4; ++t)
            #pragma unroll
            for (int r = 0; r < 4; ++r) {
                e[t][r] = __builtin_amdgcn_exp2f(s4[t][r] - m_run);
                rs += e[t][r];
            }
        rs += __shfl_xor(rs, 16);
        rs += __shfl_xor(rs, 32);
        l_run += rs;
        u32x4 paf[2];
        paf[0] = u32x4{pack2(e[0][0], e[0][1]), pack2(e[0][2], e[0][3]),
                       pack2(e[1][0], e[1][1]), pack2(e[1][2], e[1][3])};
        paf[1] = u32x4{pack2(e[2][0], e[2][1]), pack2(e[2][2], e[2][3]),
                       pack2(e[3][0], e[3][1]), pack2(e[3][2], e[3][3])};
        #pragma unroll
        for (int ks = 0; ks < 2; ++ks) {
            const frag8 pf = __builtin_bit_cast(frag8, paf[ks]);
            #pragma unroll
            for (int t = 0; t < 4; ++t) {
                const frag8 vfr = *(const frag8*)&Vlds[buf][loff2[t][ks]];
                oacc[t] = __builtin_amdgcn_mfma_f32_16x16x32_bf16(pf, vfr, oacc[t], 0, 0, 0);
            }
        }
    };

    issue_loads(0);
    write_stage(0);
    int sb = 0;
    while (true) {
        __syncthreads();
        if (sb + 1 < nb) issue_loads(sb + 1);
        step(0);
        if (sb + 1 < nb) write_stage(1);
        if (++sb >= nb) break;

        __syncthreads();
        if (sb + 1 < nb) issue_loads(sb + 1);
        step(1);
        if (sb + 1 < nb) write_stage(0);
        if (++sb >= nb) break;
    }

    const float linv = 1.f / l_run;
    #pragma unroll
    for (int r = 0; r < 4; ++r) {
        const float lr = __shfl(linv, g * 4 + r);
        float* orow = oh + (size_t)(qt * 64 + w * 16 + g * 4 + r) * Dh;
        #pragma unroll
        for (int t = 0; t < 4; ++t) orow[t * 16 + c] = oacc[t][r] * lr;
    }
}

} // namespace

extern "C" void kernel_launch(void* const* d_in, const int* in_sizes, int n_in,
                              void* d_out, int out_size, void* d_ws, size_t ws_size,
                              hipStream_t stream) {
    const float* q = (const float*)d_in[0];
    const float* k = (const float*)d_in[1];
    const float* v = (const float*)d_in[2];
    float* out = (float*)d_out;

    const size_t tensor_shorts = (size_t)BH * 32 * 4096;        // 4096 shorts per (bh,blk)
    const size_t need = 2 * tensor_shorts * sizeof(short);      // ~16.8 MB

    if (ws_size >= need) {
        short* kp = (short*)d_ws;
        short* vp = kp + tensor_shorts;
        prep_kernel<<<dim3(BH * 32), dim3(256), 0, stream>>>(k, v, kp, vp);
        battn_kernel<<<dim3(BH * NT * 2), dim3(64), 0, stream>>>(q, kp, vp, out);
    } else {
        battn_fb<<<dim3(BH * NT), dim3(256), 0, stream>>>(q, k, v, out);
    }
}